// Round 7
// baseline (202.993 us; speedup 1.0000x reference)
//
#include <hip/hip_runtime.h>

typedef __attribute__((ext_vector_type(8))) short short8;
typedef __attribute__((ext_vector_type(8))) unsigned short ushort8;
typedef __attribute__((ext_vector_type(4))) float f32x4;

static __device__ __forceinline__ unsigned short f2bf(float f) {
    union { float f; unsigned int u; } a; a.f = f;
    unsigned int u = a.u;
    return (unsigned short)((u + 0x7fffu + ((u >> 16) & 1u)) >> 16);  // RNE
}

// async global->LDS, 16B per lane; dest = wave-uniform base + lane*16 (we pass
// per-lane pointers that satisfy this). Source is per-lane arbitrary.
static __device__ __forceinline__ void gll16(const unsigned short* g, unsigned short* l) {
    __builtin_amdgcn_global_load_lds(
        (const __attribute__((address_space(1))) unsigned int*)g,
        (__attribute__((address_space(3))) unsigned int*)l, 16, 0, 0);
}

#define PROW 16640      // 130*128
#define PPLANE 2163200  // 130*PROW

// ---------------- fused: prep_sumsq (blocks 0..71) + cvt_x (blocks 72..) ----
// partial[b][rs][f] = sum_c (kern[rs][c][f]*(style[b][c]+1))^2 ; and
// x -> padded bf16 NHWC [8][130][130][128] (zero border).
__global__ void prep1(const float* __restrict__ x,
                      const float* __restrict__ kern,
                      const float* __restrict__ style,
                      float* __restrict__ partial,
                      unsigned short* __restrict__ xbf) {
    const int t = threadIdx.x;  // 256
    if (blockIdx.x < 72) {
        const int rs = blockIdx.x % 9;
        const int b  = blockIdx.x / 9;
        __shared__ float sty[128];
        __shared__ float red[256];
        if (t < 128) sty[t] = style[b * 128 + t] + 1.0f;
        __syncthreads();
        const int f = t & 127, half = t >> 7;
        const float* kp = kern + (size_t)rs * 16384 + f;
        float s = 0.0f;
        #pragma unroll 8
        for (int c = half * 64; c < half * 64 + 64; ++c) {
            float w = kp[(size_t)c * 128] * sty[c];
            s += w * w;
        }
        red[t] = s;
        __syncthreads();
        if (t < 128) partial[((size_t)b * 9 + rs) * 128 + t] = red[t] + red[t + 128];
    } else {
        const int id = (blockIdx.x - 72) * 256 + t;  // one ushort8 chunk
        if (id >= 8 * 130 * 130 * 16) return;
        const int cg = id & 15;
        const int p  = id >> 4;
        const int wp = p % 130;
        const int q  = p / 130;
        const int hp = q % 130;
        const int b  = q / 130;
        ushort8 v = {0, 0, 0, 0, 0, 0, 0, 0};
        if (hp >= 1 && hp <= 128 && wp >= 1 && wp <= 128) {
            const float4* src = (const float4*)(x + (((size_t)b * 128 + (hp - 1)) * 128 + (wp - 1)) * 128 + cg * 8);
            float4 f0 = src[0];
            float4 f1 = src[1];
            v[0] = f2bf(f0.x); v[1] = f2bf(f0.y); v[2] = f2bf(f0.z); v[3] = f2bf(f0.w);
            v[4] = f2bf(f1.x); v[5] = f2bf(f1.y); v[6] = f2bf(f1.z); v[7] = f2bf(f1.w);
        }
        *(ushort8*)(xbf + (size_t)p * 128 + cg * 8) = v;
    }
}

// Stage 2: wt[b][rs][f][c] = bf16(kern[rs][c][f] * sty[c] * demod[f]), c-contig.
__global__ void prep_wt(const float* __restrict__ kern,
                        const float* __restrict__ style,
                        const float* __restrict__ partial,
                        unsigned short* __restrict__ wt) {
    const int rs = blockIdx.x, b = blockIdx.y;
    const int t  = threadIdx.x;  // 256
    __shared__ float sty[128], dm[128];
    __shared__ float ts[32][132];
    if (t < 128) {
        sty[t] = style[b * 128 + t] + 1.0f;
    } else {
        const int f = t - 128;
        float s = 0.0f;
        #pragma unroll
        for (int r = 0; r < 9; ++r) s += partial[((size_t)b * 9 + r) * 128 + f];
        dm[f] = rsqrtf(s + 1e-8f);
    }
    __syncthreads();
    const float* kp = kern + (size_t)rs * 16384;
    unsigned short* wp = wt + ((size_t)b * 9 + rs) * 16384;
    for (int c0 = 0; c0 < 128; c0 += 32) {
        {
            const int fi = (t & 31) * 4;
            const int ci = t >> 5;
            #pragma unroll
            for (int k = 0; k < 4; ++k) {
                const float4 v = *(const float4*)(kp + (size_t)(c0 + ci + 8 * k) * 128 + fi);
                ts[ci + 8 * k][fi + 0] = v.x;
                ts[ci + 8 * k][fi + 1] = v.y;
                ts[ci + 8 * k][fi + 2] = v.z;
                ts[ci + 8 * k][fi + 3] = v.w;
            }
        }
        __syncthreads();
        {
            const int cb = (t & 7) * 4;
            const int f2 = t >> 3;
            #pragma unroll
            for (int k = 0; k < 4; ++k) {
                const int f = f2 + 32 * k;
                ushort4 o;
                o.x = f2bf(ts[cb + 0][f] * sty[c0 + cb + 0] * dm[f]);
                o.y = f2bf(ts[cb + 1][f] * sty[c0 + cb + 1] * dm[f]);
                o.z = f2bf(ts[cb + 2][f] * sty[c0 + cb + 2] * dm[f]);
                o.w = f2bf(ts[cb + 3][f] * sty[c0 + cb + 3] * dm[f]);
                *(ushort4*)(wp + (size_t)f * 128 + c0 + cb) = o;
            }
        }
        __syncthreads();
    }
}

// ---------------- main conv v8: v6 geometry + conflict-free LDS layout ------
// 1024 blocks (b = lin&7 -> XCD, h = lin>>3), 256 thr = 4 waves, 4 blocks/CU.
// Block tile: one h-row, 128w x 128f. Wave (2x2): 64w x 64f, acc[4][4]=64.
// Per K-step (36 = 9 taps x 4 c-chunks of 32): stage A(8KB)+B(8KB) into buf^1
// via global_load_lds(16B), ds_read frags, 16 MFMAs, one __syncthreads.
// LDS layout CHUNK-TRANSPOSED (proven in v7: conflicts 4.72M -> 0): 16B chunk
// (w,q) at index q*128+w, so each 16-lane phase of ds_read_b128 covers 256
// consecutive bytes (2-way = free). v6's w-major layout was 4-way (+4cy/read).
// 4 blocks/CU (not v7's 2): independent barrier groups hide each other's
// vmcnt-drain at __syncthreads — v7 proved 2/CU loses 40% to lockstep.
__global__ __launch_bounds__(256, 4) void mdconv8(const unsigned short* __restrict__ xbf,
                                                  const unsigned short* __restrict__ wt,
                                                  float* __restrict__ out) {
    const int lin = blockIdx.x;   // [0,1024)
    const int b   = lin & 7;      // XCD-locality: batch == XCD
    const int h   = lin >> 3;     // output h-row [0,128)
    const int tid = threadIdx.x;

    __shared__ unsigned short lsh[2 * 8192];  // 32,768 B: [buf][A 4096 | B 4096] els

    const unsigned short* xb  = xbf + (size_t)b * PPLANE;
    const unsigned short* wtb = wt + (size_t)b * 9 * 16384;

    // staging: thread t stages LDS chunks t and t+256 of each tile.
    // LDS chunk I = q*128 + w  (q = I>>7, w = I&127); source el = w*128 + q*8.
    // chunk t   : src = (t&127)*128 + (t>>7)*8        dest el = t*8
    // chunk t+256: q+=2 -> src += 16                   dest el = 2048 + t*8
    const int so = (tid & 127) * 128 + (tid >> 7) * 8;

    const int lane = tid & 63;
    const int wv   = tid >> 6;       // 2x2 waves
    const int fl   = lane & 15;
    const int quad = lane >> 4;
    const int wrb  = (wv >> 1) * 64; // w base
    const int fcb  = (wv & 1) * 64;  // f base
    // fragment (w = wrb + mt*16 + fl, c = quad*8..) = chunk (w, quad):
    const int ab_rd = quad * 1024 + (wrb + fl) * 8;         // + cur*8192 + mt*128
    const int bb_rd = 4096 + quad * 1024 + (fcb + fl) * 8;  // + cur*8192 + ft*128

    f32x4 acc[4][4];
    #pragma unroll
    for (int mt = 0; mt < 4; ++mt)
        #pragma unroll
        for (int ft = 0; ft < 4; ++ft)
            acc[mt][ft] = (f32x4){0.f, 0.f, 0.f, 0.f};

    // step st: rs = st>>2 (tap), kc = st&3 (c-chunk)
#define STAGE(st, nxt) {                                                          \
    const int rs_ = (st) >> 2, kc_ = (st) & 3;                                    \
    const int r_ = rs_ / 3, s_ = rs_ % 3;                                         \
    const unsigned short* ga = xb + ((size_t)(h + r_) * 130 + s_) * 128 + kc_ * 32; \
    const unsigned short* gb = wtb + rs_ * 16384 + kc_ * 32;                      \
    unsigned short* la = lsh + (nxt) * 8192;                                      \
    gll16(ga + so,      la + tid * 8);                                            \
    gll16(ga + so + 16, la + 2048 + tid * 8);                                     \
    gll16(gb + so,      la + 4096 + tid * 8);                                     \
    gll16(gb + so + 16, la + 6144 + tid * 8);                                     \
}

    STAGE(0, 0);
    __syncthreads();  // drains vmcnt (barrier semantics)

    #pragma unroll
    for (int st = 0; st < 36; ++st) {
        const int cur = st & 1;
        if (st < 35) STAGE(st + 1, cur ^ 1);
        const int ce = cur * 8192;
        short8 bv[4];
        #pragma unroll
        for (int ft = 0; ft < 4; ++ft)
            bv[ft] = *(const short8*)(lsh + ce + bb_rd + ft * 128);
        #pragma unroll
        for (int mt = 0; mt < 4; ++mt) {
            const short8 av = *(const short8*)(lsh + ce + ab_rd + mt * 128);
            #pragma unroll
            for (int ft = 0; ft < 4; ++ft)
                acc[mt][ft] = __builtin_amdgcn_mfma_f32_16x16x32_bf16(av, bv[ft], acc[mt][ft], 0, 0, 0);
        }
        __syncthreads();  // one barrier/step
    }
#undef STAGE

    // D: col=lane&15 -> f-within-tile, row=quad*4+reg -> w-within-Mtile.
    float* ob = out + ((size_t)(b * 128 + h) * 128) * 128;
    #pragma unroll
    for (int mt = 0; mt < 4; ++mt) {
        #pragma unroll
        for (int reg = 0; reg < 4; ++reg) {
            const int w = wrb + mt * 16 + quad * 4 + reg;
            #pragma unroll
            for (int ft = 0; ft < 4; ++ft)
                ob[(size_t)w * 128 + fcb + ft * 16 + fl] = acc[mt][ft][reg];
        }
    }
}

// ---------------- R2 fallback (used only if ws too small) ----------------
__global__ void prep_sumsq(const float* __restrict__ kern,
                           const float* __restrict__ style,
                           float* __restrict__ partial) {
    const int rs = blockIdx.x;
    const int b  = blockIdx.y;
    const int t  = threadIdx.x;
    __shared__ float sty[128];
    __shared__ float red[256];
    if (t < 128) sty[t] = style[b * 128 + t] + 1.0f;
    __syncthreads();
    const int f = t & 127, half = t >> 7;
    const float* kp = kern + (size_t)rs * 16384 + f;
    float s = 0.0f;
    #pragma unroll 8
    for (int c = half * 64; c < half * 64 + 64; ++c) {
        float w = kp[(size_t)c * 128] * sty[c];
        s += w * w;
    }
    red[t] = s;
    __syncthreads();
    if (t < 128) partial[((size_t)b * 9 + rs) * 128 + t] = red[t] + red[t + 128];
}

__global__ void mdconv_fb(const float* __restrict__ x,
                          const unsigned short* __restrict__ wt,
                          float* __restrict__ out) {
    const int lin = blockIdx.x;
    const int b   = lin & 7;
    const int sp  = lin >> 3;
    const int h0  = (sp >> 3) * 8;
    const int w0  = (sp & 7) * 16;
    const int tid = threadIdx.x;
    __shared__ unsigned short xs[180 * 138];
    {
        const float* xb = x + (size_t)b * (128 * 128 * 128);
        for (int id = tid; id < 180 * 16; id += 256) {
            int p  = id >> 4;
            int cg = id & 15;
            int pr = p / 18;
            int pc = p - pr * 18;
            int hh = h0 - 1 + pr;
            int ww = w0 - 1 + pc;
            ushort8 v = {0, 0, 0, 0, 0, 0, 0, 0};
            if ((unsigned)hh < 128u && (unsigned)ww < 128u) {
                const float4* src = (const float4*)(xb + ((size_t)(hh * 128 + ww) * 128 + cg * 8));
                float4 f0 = src[0];
                float4 f1 = src[1];
                v[0] = f2bf(f0.x); v[1] = f2bf(f0.y); v[2] = f2bf(f0.z); v[3] = f2bf(f0.w);
                v[4] = f2bf(f1.x); v[5] = f2bf(f1.y); v[6] = f2bf(f1.z); v[7] = f2bf(f1.w);
            }
            *(ushort8*)(xs + p * 138 + cg * 8) = v;
        }
    }
    __syncthreads();
    const int lane = tid & 63;
    const int wave = tid >> 6;
    const int fl   = lane & 15;
    const int quad = lane >> 4;
    const int kq   = quad * 8;
    f32x4 acc[8][2];
    #pragma unroll
    for (int mt = 0; mt < 8; ++mt)
        #pragma unroll
        for (int j = 0; j < 2; ++j)
            acc[mt][j] = (f32x4){0.f, 0.f, 0.f, 0.f};
    const unsigned short* wtb = wt + (size_t)b * (9 * 128 * 128) + (size_t)wave * 4096 + fl * 128 + kq;
    #pragma unroll
    for (int rs = 0; rs < 9; ++rs) {
        const int r = rs / 3, s = rs % 3;
        #pragma unroll
        for (int kc = 0; kc < 4; ++kc) {
            const int k0 = kc * 32 + kq;
            short8 a[8];
            #pragma unroll
            for (int mt = 0; mt < 8; ++mt)
                a[mt] = *(const short8*)(xs + ((mt + r) * 18 + fl + s) * 138 + k0);
            #pragma unroll
            for (int j = 0; j < 2; ++j) {
                short8 bf = *(const short8*)(wtb + rs * 16384 + j * 2048 + kc * 32);
                #pragma unroll
                for (int mt = 0; mt < 8; ++mt)
                    acc[mt][j] = __builtin_amdgcn_mfma_f32_16x16x32_bf16(a[mt], bf, acc[mt][j], 0, 0, 0);
            }
        }
    }
    float* ob = out + ((size_t)(b * 128 + h0) * 128 + w0) * 128;
    #pragma unroll
    for (int mt = 0; mt < 8; ++mt)
        #pragma unroll
        for (int j = 0; j < 2; ++j) {
            const int f = (wave * 2 + j) * 16 + fl;
            #pragma unroll
            for (int reg = 0; reg < 4; ++reg)
                ob[((size_t)(mt * 128 + quad * 4 + reg)) * 128 + f] = acc[mt][j][reg];
        }
}

extern "C" void kernel_launch(void* const* d_in, const int* in_sizes, int n_in,
                              void* d_out, int out_size, void* d_ws, size_t ws_size,
                              hipStream_t stream) {
    const float* x     = (const float*)d_in[0];
    const float* style = (const float*)d_in[1];
    const float* kern  = (const float*)d_in[2];
    float* out = (float*)d_out;

    const size_t XBF_BYTES = (size_t)8 * 130 * 130 * 128 * 2;  // 34,611,200
    const size_t WT_BYTES  = (size_t)8 * 9 * 128 * 128 * 2;    //  2,359,296
    const size_t NEED      = XBF_BYTES + WT_BYTES + 36864;

    if (ws_size >= NEED) {
        unsigned short* xbf = (unsigned short*)d_ws;
        unsigned short* wt  = (unsigned short*)((char*)d_ws + XBF_BYTES);
        float* partial      = (float*)((char*)d_ws + XBF_BYTES + WT_BYTES);
        prep1<<<dim3(72 + 8450), dim3(256), 0, stream>>>(x, kern, style, partial, xbf);
        prep_wt<<<dim3(9, 8), dim3(256), 0, stream>>>(kern, style, partial, wt);
        mdconv8<<<dim3(1024), dim3(256), 0, stream>>>(xbf, wt, out);
    } else {
        unsigned short* wt = (unsigned short*)d_ws;
        float* partial     = (float*)((char*)d_ws + WT_BYTES);
        prep_sumsq<<<dim3(9, 8), dim3(256), 0, stream>>>(kern, style, partial);
        prep_wt<<<dim3(9, 8), dim3(256), 0, stream>>>(kern, style, partial, wt);
        mdconv_fb<<<dim3(1024), dim3(256), 0, stream>>>(x, wt, out);
    }
}

// Round 8
// 164.279 us; speedup vs baseline: 1.2357x; 1.2357x over previous
//
#include <hip/hip_runtime.h>

typedef __attribute__((ext_vector_type(8))) short short8;
typedef __attribute__((ext_vector_type(8))) unsigned short ushort8;
typedef __attribute__((ext_vector_type(4))) float f32x4;

static __device__ __forceinline__ unsigned short f2bf(float f) {
    union { float f; unsigned int u; } a; a.f = f;
    unsigned int u = a.u;
    return (unsigned short)((u + 0x7fffu + ((u >> 16) & 1u)) >> 16);  // RNE
}

// async global->LDS, 16B per lane; dest = wave-uniform base + lane*16 (we pass
// per-lane pointers that satisfy this). Source is per-lane arbitrary.
static __device__ __forceinline__ void gll16(const unsigned short* g, unsigned short* l) {
    __builtin_amdgcn_global_load_lds(
        (const __attribute__((address_space(1))) unsigned int*)g,
        (__attribute__((address_space(3))) unsigned int*)l, 16, 0, 0);
}

#define PROW 16640      // 130*128
#define PPLANE 2163200  // 130*PROW

// ---------------- fused: prep_sumsq (blocks 0..71) + cvt_x (blocks 72..) ----
__global__ void prep1(const float* __restrict__ x,
                      const float* __restrict__ kern,
                      const float* __restrict__ style,
                      float* __restrict__ partial,
                      unsigned short* __restrict__ xbf) {
    const int t = threadIdx.x;  // 256
    if (blockIdx.x < 72) {
        const int rs = blockIdx.x % 9;
        const int b  = blockIdx.x / 9;
        __shared__ float sty[128];
        __shared__ float red[256];
        if (t < 128) sty[t] = style[b * 128 + t] + 1.0f;
        __syncthreads();
        const int f = t & 127, half = t >> 7;
        const float* kp = kern + (size_t)rs * 16384 + f;
        float s = 0.0f;
        #pragma unroll 8
        for (int c = half * 64; c < half * 64 + 64; ++c) {
            float w = kp[(size_t)c * 128] * sty[c];
            s += w * w;
        }
        red[t] = s;
        __syncthreads();
        if (t < 128) partial[((size_t)b * 9 + rs) * 128 + t] = red[t] + red[t + 128];
    } else {
        const int id = (blockIdx.x - 72) * 256 + t;  // one ushort8 chunk
        if (id >= 8 * 130 * 130 * 16) return;
        const int cg = id & 15;
        const int p  = id >> 4;
        const int wp = p % 130;
        const int q  = p / 130;
        const int hp = q % 130;
        const int b  = q / 130;
        ushort8 v = {0, 0, 0, 0, 0, 0, 0, 0};
        if (hp >= 1 && hp <= 128 && wp >= 1 && wp <= 128) {
            const float4* src = (const float4*)(x + (((size_t)b * 128 + (hp - 1)) * 128 + (wp - 1)) * 128 + cg * 8);
            float4 f0 = src[0];
            float4 f1 = src[1];
            v[0] = f2bf(f0.x); v[1] = f2bf(f0.y); v[2] = f2bf(f0.z); v[3] = f2bf(f0.w);
            v[4] = f2bf(f1.x); v[5] = f2bf(f1.y); v[6] = f2bf(f1.z); v[7] = f2bf(f1.w);
        }
        *(ushort8*)(xbf + (size_t)p * 128 + cg * 8) = v;
    }
}

// Stage 2: wt[b][rs][f][c] = bf16(kern[rs][c][f] * sty[c] * demod[f]), c-contig.
__global__ void prep_wt(const float* __restrict__ kern,
                        const float* __restrict__ style,
                        const float* __restrict__ partial,
                        unsigned short* __restrict__ wt) {
    const int rs = blockIdx.x, b = blockIdx.y;
    const int t  = threadIdx.x;  // 256
    __shared__ float sty[128], dm[128];
    __shared__ float ts[32][132];
    if (t < 128) {
        sty[t] = style[b * 128 + t] + 1.0f;
    } else {
        const int f = t - 128;
        float s = 0.0f;
        #pragma unroll
        for (int r = 0; r < 9; ++r) s += partial[((size_t)b * 9 + r) * 128 + f];
        dm[f] = rsqrtf(s + 1e-8f);
    }
    __syncthreads();
    const float* kp = kern + (size_t)rs * 16384;
    unsigned short* wp = wt + ((size_t)b * 9 + rs) * 16384;
    for (int c0 = 0; c0 < 128; c0 += 32) {
        {
            const int fi = (t & 31) * 4;
            const int ci = t >> 5;
            #pragma unroll
            for (int k = 0; k < 4; ++k) {
                const float4 v = *(const float4*)(kp + (size_t)(c0 + ci + 8 * k) * 128 + fi);
                ts[ci + 8 * k][fi + 0] = v.x;
                ts[ci + 8 * k][fi + 1] = v.y;
                ts[ci + 8 * k][fi + 2] = v.z;
                ts[ci + 8 * k][fi + 3] = v.w;
            }
        }
        __syncthreads();
        {
            const int cb = (t & 7) * 4;
            const int f2 = t >> 3;
            #pragma unroll
            for (int k = 0; k < 4; ++k) {
                const int f = f2 + 32 * k;
                ushort4 o;
                o.x = f2bf(ts[cb + 0][f] * sty[c0 + cb + 0] * dm[f]);
                o.y = f2bf(ts[cb + 1][f] * sty[c0 + cb + 1] * dm[f]);
                o.z = f2bf(ts[cb + 2][f] * sty[c0 + cb + 2] * dm[f]);
                o.w = f2bf(ts[cb + 3][f] * sty[c0 + cb + 3] * dm[f]);
                *(ushort4*)(wp + (size_t)f * 128 + c0 + cb) = o;
            }
        }
        __syncthreads();
    }
}

// ---------------- main conv v9: v6 geometry + XOR-swizzled LDS (coalesced) --
// 1024 blocks (b = lin&7 -> XCD, h = lin>>3), 256 thr = 4 waves, 4 blocks/CU.
// Block tile: one h-row, 128w x 128f. Wave (2x2): 64w x 64f, acc[4][4]=64.
// LDS layout: 16B chunk (w,q) at index I = w*4 + (q ^ ((w>>1)&3)).
//  - staging source: 4 chunks per 64B row-block, permuted WITHIN the block ->
//    source coalescing identical to v6 (16x 64B segments per wave-inst).
//    (v8's transpose scattered source to 64x 16B @256B stride -> 4x L2 reqs,
//    96us. v6's unswizzled layout was a 4-way read conflict, +4cy/read.)
//  - read phase (8 lanes, fixed quad): addr%128 = 64*(fl&1) + 16*(quad^((fl>>1)&3))
//    -> 8 distinct 16B slots -> conflict-free.
__global__ __launch_bounds__(256, 4) void mdconv9(const unsigned short* __restrict__ xbf,
                                                  const unsigned short* __restrict__ wt,
                                                  float* __restrict__ out) {
    const int lin = blockIdx.x;   // [0,1024)
    const int b   = lin & 7;      // XCD-locality: batch == XCD
    const int h   = lin >> 3;     // output h-row [0,128)
    const int tid = threadIdx.x;

    __shared__ unsigned short lsh[2 * 8192];  // 32,768 B: [buf][A 4096 | B 4096] els

    const unsigned short* xb  = xbf + (size_t)b * PPLANE;
    const unsigned short* wtb = wt + (size_t)b * 9 * 16384;

    // staging: thread t owns LDS chunks t and t+256 of each tile (dest linear).
    // chunk I -> (w = I>>2, q = (I&3) ^ ((w>>1)&3)); source el = w*128 + q*8.
    // chunk t+256: w += 64 -> swizzle term unchanged -> source = so + 8192.
    const int w_ = tid >> 2;
    const int q_ = (tid & 3) ^ ((w_ >> 1) & 3);
    const int so = w_ * 128 + q_ * 8;

    const int lane = tid & 63;
    const int wv   = tid >> 6;       // 2x2 waves
    const int fl   = lane & 15;
    const int quad = lane >> 4;
    const int wrb  = (wv >> 1) * 64; // w base
    const int fcb  = (wv & 1) * 64;  // f base
    // fragment (w = wrb+mt*16+fl, q = quad): LDS el = w*32 + 8*(quad^((w>>1)&3));
    // (w>>1)&3 == (fl>>1)&3 since wrb, mt*16 are multiples of 8.
    const int xq    = (quad ^ ((fl >> 1) & 3)) * 8;
    const int ab_rd = (wrb + fl) * 32 + xq;         // + cur*8192 + mt*512
    const int bb_rd = 4096 + (fcb + fl) * 32 + xq;  // + cur*8192 + ft*512

    f32x4 acc[4][4];
    #pragma unroll
    for (int mt = 0; mt < 4; ++mt)
        #pragma unroll
        for (int ft = 0; ft < 4; ++ft)
            acc[mt][ft] = (f32x4){0.f, 0.f, 0.f, 0.f};

    // step st: rs = st>>2 (tap), kc = st&3 (c-chunk)
#define STAGE(st, nxt) {                                                          \
    const int rs_ = (st) >> 2, kc_ = (st) & 3;                                    \
    const int r_ = rs_ / 3, s_ = rs_ % 3;                                         \
    const unsigned short* ga = xb + ((size_t)(h + r_) * 130 + s_) * 128 + kc_ * 32; \
    const unsigned short* gb = wtb + rs_ * 16384 + kc_ * 32;                      \
    unsigned short* la = lsh + (nxt) * 8192;                                      \
    gll16(ga + so,        la + tid * 8);                                          \
    gll16(ga + so + 8192, la + 2048 + tid * 8);                                   \
    gll16(gb + so,        la + 4096 + tid * 8);                                   \
    gll16(gb + so + 8192, la + 6144 + tid * 8);                                   \
}

    STAGE(0, 0);
    __syncthreads();  // drains vmcnt (barrier semantics)

    #pragma unroll
    for (int st = 0; st < 36; ++st) {
        const int cur = st & 1;
        if (st < 35) STAGE(st + 1, cur ^ 1);
        const int ce = cur * 8192;
        short8 bv[4];
        #pragma unroll
        for (int ft = 0; ft < 4; ++ft)
            bv[ft] = *(const short8*)(lsh + ce + bb_rd + ft * 512);
        #pragma unroll
        for (int mt = 0; mt < 4; ++mt) {
            const short8 av = *(const short8*)(lsh + ce + ab_rd + mt * 512);
            #pragma unroll
            for (int ft = 0; ft < 4; ++ft)
                acc[mt][ft] = __builtin_amdgcn_mfma_f32_16x16x32_bf16(av, bv[ft], acc[mt][ft], 0, 0, 0);
        }
        __syncthreads();  // one barrier/step
    }
#undef STAGE

    // D: col=lane&15 -> f-within-tile, row=quad*4+reg -> w-within-Mtile.
    float* ob = out + ((size_t)(b * 128 + h) * 128) * 128;
    #pragma unroll
    for (int mt = 0; mt < 4; ++mt) {
        #pragma unroll
        for (int reg = 0; reg < 4; ++reg) {
            const int w = wrb + mt * 16 + quad * 4 + reg;
            #pragma unroll
            for (int ft = 0; ft < 4; ++ft)
                ob[(size_t)w * 128 + fcb + ft * 16 + fl] = acc[mt][ft][reg];
        }
    }
}

// ---------------- R2 fallback (used only if ws too small) ----------------
__global__ void prep_sumsq(const float* __restrict__ kern,
                           const float* __restrict__ style,
                           float* __restrict__ partial) {
    const int rs = blockIdx.x;
    const int b  = blockIdx.y;
    const int t  = threadIdx.x;
    __shared__ float sty[128];
    __shared__ float red[256];
    if (t < 128) sty[t] = style[b * 128 + t] + 1.0f;
    __syncthreads();
    const int f = t & 127, half = t >> 7;
    const float* kp = kern + (size_t)rs * 16384 + f;
    float s = 0.0f;
    #pragma unroll 8
    for (int c = half * 64; c < half * 64 + 64; ++c) {
        float w = kp[(size_t)c * 128] * sty[c];
        s += w * w;
    }
    red[t] = s;
    __syncthreads();
    if (t < 128) partial[((size_t)b * 9 + rs) * 128 + t] = red[t] + red[t + 128];
}

__global__ void mdconv_fb(const float* __restrict__ x,
                          const unsigned short* __restrict__ wt,
                          float* __restrict__ out) {
    const int lin = blockIdx.x;
    const int b   = lin & 7;
    const int sp  = lin >> 3;
    const int h0  = (sp >> 3) * 8;
    const int w0  = (sp & 7) * 16;
    const int tid = threadIdx.x;
    __shared__ unsigned short xs[180 * 138];
    {
        const float* xb = x + (size_t)b * (128 * 128 * 128);
        for (int id = tid; id < 180 * 16; id += 256) {
            int p  = id >> 4;
            int cg = id & 15;
            int pr = p / 18;
            int pc = p - pr * 18;
            int hh = h0 - 1 + pr;
            int ww = w0 - 1 + pc;
            ushort8 v = {0, 0, 0, 0, 0, 0, 0, 0};
            if ((unsigned)hh < 128u && (unsigned)ww < 128u) {
                const float4* src = (const float4*)(xb + ((size_t)(hh * 128 + ww) * 128 + cg * 8));
                float4 f0 = src[0];
                float4 f1 = src[1];
                v[0] = f2bf(f0.x); v[1] = f2bf(f0.y); v[2] = f2bf(f0.z); v[3] = f2bf(f0.w);
                v[4] = f2bf(f1.x); v[5] = f2bf(f1.y); v[6] = f2bf(f1.z); v[7] = f2bf(f1.w);
            }
            *(ushort8*)(xs + p * 138 + cg * 8) = v;
        }
    }
    __syncthreads();
    const int lane = tid & 63;
    const int wave = tid >> 6;
    const int fl   = lane & 15;
    const int quad = lane >> 4;
    const int kq   = quad * 8;
    f32x4 acc[8][2];
    #pragma unroll
    for (int mt = 0; mt < 8; ++mt)
        #pragma unroll
        for (int j = 0; j < 2; ++j)
            acc[mt][j] = (f32x4){0.f, 0.f, 0.f, 0.f};
    const unsigned short* wtb = wt + (size_t)b * (9 * 128 * 128) + (size_t)wave * 4096 + fl * 128 + kq;
    #pragma unroll
    for (int rs = 0; rs < 9; ++rs) {
        const int r = rs / 3, s = rs % 3;
        #pragma unroll
        for (int kc = 0; kc < 4; ++kc) {
            const int k0 = kc * 32 + kq;
            short8 a[8];
            #pragma unroll
            for (int mt = 0; mt < 8; ++mt)
                a[mt] = *(const short8*)(xs + ((mt + r) * 18 + fl + s) * 138 + k0);
            #pragma unroll
            for (int j = 0; j < 2; ++j) {
                short8 bf = *(const short8*)(wtb + rs * 16384 + j * 2048 + kc * 32);
                #pragma unroll
                for (int mt = 0; mt < 8; ++mt)
                    acc[mt][j] = __builtin_amdgcn_mfma_f32_16x16x32_bf16(a[mt], bf, acc[mt][j], 0, 0, 0);
            }
        }
    }
    float* ob = out + ((size_t)(b * 128 + h0) * 128 + w0) * 128;
    #pragma unroll
    for (int mt = 0; mt < 8; ++mt)
        #pragma unroll
        for (int j = 0; j < 2; ++j) {
            const int f = (wave * 2 + j) * 16 + fl;
            #pragma unroll
            for (int reg = 0; reg < 4; ++reg)
                ob[((size_t)(mt * 128 + quad * 4 + reg)) * 128 + f] = acc[mt][j][reg];
        }
}

extern "C" void kernel_launch(void* const* d_in, const int* in_sizes, int n_in,
                              void* d_out, int out_size, void* d_ws, size_t ws_size,
                              hipStream_t stream) {
    const float* x     = (const float*)d_in[0];
    const float* style = (const float*)d_in[1];
    const float* kern  = (const float*)d_in[2];
    float* out = (float*)d_out;

    const size_t XBF_BYTES = (size_t)8 * 130 * 130 * 128 * 2;  // 34,611,200
    const size_t WT_BYTES  = (size_t)8 * 9 * 128 * 128 * 2;    //  2,359,296
    const size_t NEED      = XBF_BYTES + WT_BYTES + 36864;

    if (ws_size >= NEED) {
        unsigned short* xbf = (unsigned short*)d_ws;
        unsigned short* wt  = (unsigned short*)((char*)d_ws + XBF_BYTES);
        float* partial      = (float*)((char*)d_ws + XBF_BYTES + WT_BYTES);
        prep1<<<dim3(72 + 8450), dim3(256), 0, stream>>>(x, kern, style, partial, xbf);
        prep_wt<<<dim3(9, 8), dim3(256), 0, stream>>>(kern, style, partial, wt);
        mdconv9<<<dim3(1024), dim3(256), 0, stream>>>(xbf, wt, out);
    } else {
        unsigned short* wt = (unsigned short*)d_ws;
        float* partial     = (float*)((char*)d_ws + WT_BYTES);
        prep_sumsq<<<dim3(9, 8), dim3(256), 0, stream>>>(kern, style, partial);
        prep_wt<<<dim3(9, 8), dim3(256), 0, stream>>>(kern, style, partial, wt);
        mdconv_fb<<<dim3(1024), dim3(256), 0, stream>>>(x, wt, out);
    }
}